// Round 6
// baseline (984.520 us; speedup 1.0000x reference)
//
#include <hip/hip_runtime.h>
#include <cmath>

// PairList forward: n atoms, P = n(n-1)/2 pairs in triu(k=1) row-major order.
// Output (float32, concatenated flat, 7P elements):
//   [0,P)   pair row0: i or -1        [P,2P)  pair row1: j or -1
//   [2P,3P) d_ij*valid                [3P,6P) r_ij*valid (P,3 row-major)
//   [6P,7P) valid as 0/1
// valid = (sub[i]==sub[j]) && (|pos[j]-pos[i]| < 5).
//
// Fused single-pass over the output (each line written exactly once).
// runEnd[i] (first index after i's subsystem run) is precomputed into d_ws so
// the ~98.5% all-invalid thread-groups need ZERO per-pair memory traffic:
// condition (j >= runEnd[i]) with sorted subsystem ids means all 8 pairs of
// the group are cross-subsystem -> 14 constant nontemporal float4 stores.

typedef float f4_t __attribute__((ext_vector_type(4)));

__device__ __forceinline__ void nts(float* p, float a, float b, float c, float d) {
  f4_t v = {a, b, c, d};
  __builtin_nontemporal_store(v, reinterpret_cast<f4_t*>(p));
}
__device__ __forceinline__ void nts1(float* p, float x) {
  f4_t v = {x, x, x, x};
  __builtin_nontemporal_store(v, reinterpret_cast<f4_t*>(p));
}

__global__ __launch_bounds__(256) void runend_kernel(
    const int* __restrict__ sub, int* __restrict__ re, int n) {
  int a = blockIdx.x * blockDim.x + threadIdx.x;
  if (a >= n) return;
  const int shift = (sub[n - 1] == 0) ? 1 : 0;  // int64 words vs int32
  int s = sub[a << shift];
  int lo = a + 1, hi = n;                        // first idx>a with sub>s
  while (lo < hi) {
    int mid = (lo + hi) >> 1;
    if (sub[mid << shift] > s) hi = mid; else lo = mid + 1;
  }
  re[a] = lo;
}

template <bool USE_RE>
__global__ __launch_bounds__(256) void pairlist_kernel(
    const float* __restrict__ pos, const int* __restrict__ sub,
    const int* __restrict__ runEnd, float* __restrict__ out,
    int n, long long P) {
  long long g  = (long long)blockIdx.x * blockDim.x + threadIdx.x;
  long long p0 = g * 8;
  if (p0 >= P) return;

  const int shift = (sub[n - 1] == 0) ? 1 : 0;

  // Invert triangular linear index -> row i (double sqrt + exact fixup).
  double t = 2.0 * (double)n - 1.0;
  double disc = t * t - 8.0 * (double)p0;
  int i = (int)((t - sqrt(disc)) * 0.5);
  if (i < 0) i = 0;
  if (i > n - 2) i = n - 2;
  auto T = [n](long long ii) { return ii * (2LL * n - ii - 1) / 2; };
  while (T(i + 1) <= p0) ++i;
  while (i > 0 && T(i) > p0) --i;
  int j = (int)((long long)i + 1 + (p0 - T(i)));

  float* oi  = out;
  float* oj  = out + P;
  float* od  = out + 2 * P;
  float* orr = out + 3 * P;
  float* ov  = out + 6 * P;

  int re;
  if (USE_RE) re = runEnd[i];
  else {
    // sorted ids: sub[j] != sub[i] (j>i) implies all later j also differ
    re = (sub[j << shift] == sub[i << shift]) ? n : j;
  }

  // Fast path: whole group cross-subsystem, no row advance -> constants only.
  if (j >= re && p0 + 8 <= P && j + 8 <= n) {
    nts1(oi + p0, -1.f);  nts1(oi + p0 + 4, -1.f);
    nts1(oj + p0, -1.f);  nts1(oj + p0 + 4, -1.f);
    nts1(od + p0, 0.f);   nts1(od + p0 + 4, 0.f);
    nts1(ov + p0, 0.f);   nts1(ov + p0 + 4, 0.f);
    float* rb = orr + 3 * p0;
#pragma unroll
    for (int q = 0; q < 6; ++q) nts1(rb + 4 * q, 0.f);
    return;
  }

  int   si  = sub[i << shift];
  float pix = pos[3 * i], piy = pos[3 * i + 1], piz = pos[3 * i + 2];

  float fi[8], fj[8], fd[8], fv[8], fr[24];

#pragma unroll
  for (int k = 0; k < 8; ++k) {
    long long p = p0 + k;
    float vi = -1.0f, vj = -1.0f, vd = 0.0f, vv = 0.0f;
    float rx = 0.0f, ry = 0.0f, rz = 0.0f;
    if (p < P) {
      bool insys = USE_RE ? (j < re) : (sub[j << shift] == si);
      if (insys) {
        float dx = pos[3 * j]     - pix;
        float dy = pos[3 * j + 1] - piy;
        float dz = pos[3 * j + 2] - piz;
        float dd = sqrtf(dx * dx + dy * dy + dz * dz);
        if (dd < 5.0f) {
          vi = (float)i; vj = (float)j;
          vd = dd; vv = 1.0f;
          rx = dx; ry = dy; rz = dz;
        }
      }
      ++j;
      if (j >= n) {                       // row advance (rare)
        ++i;
        j = i + 1;
        if (i < n - 1) {
          si  = sub[i << shift];
          if (USE_RE) re = runEnd[i];
          pix = pos[3 * i]; piy = pos[3 * i + 1]; piz = pos[3 * i + 2];
        }
      }
    }
    fi[k] = vi; fj[k] = vj; fd[k] = vd; fv[k] = vv;
    fr[3 * k] = rx; fr[3 * k + 1] = ry; fr[3 * k + 2] = rz;
  }

  if (p0 + 8 <= P) {
    nts(oi + p0,     fi[0], fi[1], fi[2], fi[3]);
    nts(oi + p0 + 4, fi[4], fi[5], fi[6], fi[7]);
    nts(oj + p0,     fj[0], fj[1], fj[2], fj[3]);
    nts(oj + p0 + 4, fj[4], fj[5], fj[6], fj[7]);
    nts(od + p0,     fd[0], fd[1], fd[2], fd[3]);
    nts(od + p0 + 4, fd[4], fd[5], fd[6], fd[7]);
    nts(ov + p0,     fv[0], fv[1], fv[2], fv[3]);
    nts(ov + p0 + 4, fv[4], fv[5], fv[6], fv[7]);
    float* rb = orr + 3 * p0;
#pragma unroll
    for (int q = 0; q < 6; ++q)
      nts(rb + 4 * q, fr[4 * q], fr[4 * q + 1], fr[4 * q + 2], fr[4 * q + 3]);
  } else {
    for (int k = 0; k < 8 && p0 + k < P; ++k) {
      long long p = p0 + k;
      oi[p] = fi[k]; oj[p] = fj[k]; od[p] = fd[k]; ov[p] = fv[k];
      orr[3 * p] = fr[3 * k]; orr[3 * p + 1] = fr[3 * k + 1]; orr[3 * p + 2] = fr[3 * k + 2];
    }
  }
}

extern "C" void kernel_launch(void* const* d_in, const int* in_sizes, int n_in,
                              void* d_out, int out_size, void* d_ws, size_t ws_size,
                              hipStream_t stream) {
  const float* pos = (const float*)d_in[0];
  const int*   sub = (const int*)d_in[1];
  float* out = (float*)d_out;

  // Geometry from out_size: out_size = 7P, P = n(n-1)/2.
  long long P = (long long)out_size / 7;
  int n = (int)((1.0 + sqrt(1.0 + 8.0 * (double)P)) * 0.5 + 0.5);
  if ((long long)n * (n - 1) / 2 != P) {        // fallback
    n = in_sizes[0] / 3;
    P = (long long)n * (n - 1) / 2;
  }

  long long threads = (P + 7) / 8;
  int blocks = (int)((threads + 255) / 256);

  bool useRe = (ws_size >= (size_t)n * sizeof(int));
  if (useRe) {
    int* re = (int*)d_ws;
    hipLaunchKernelGGL(runend_kernel, dim3((n + 255) / 256), dim3(256), 0,
                       stream, sub, re, n);
    hipLaunchKernelGGL((pairlist_kernel<true>), dim3(blocks), dim3(256), 0,
                       stream, pos, sub, re, out, n, P);
  } else {
    hipLaunchKernelGGL((pairlist_kernel<false>), dim3(blocks), dim3(256), 0,
                       stream, pos, sub, (const int*)nullptr, out, n, P);
  }
}

// Round 7
// 201.063 us; speedup vs baseline: 4.8966x; 4.8966x over previous
//
#include <hip/hip_runtime.h>
#include <cmath>

// PairList forward: n atoms, P = n(n-1)/2 pairs in triu(k=1) row-major order.
// Output (float32, concatenated flat, 7P elements):
//   [0,P)   pair row0: i or -1        [P,2P)  pair row1: j or -1
//   [2P,3P) d_ij*valid                [3P,6P) r_ij*valid (P,3 row-major)
//   [6P,7P) valid as 0/1
// valid = (sub[i]==sub[j]) && (|pos[j]-pos[i]| < 5).
//
// Structure: runend_kernel precomputes runEnd[i] = first index after atom i's
// (sorted) subsystem run. Main kernel: 4 pairs/thread, flat triangular index;
// ~98.5% of threads hit the all-invalid fast path = 7 coalesced float4 stores
// of constants with ZERO data loads (runEnd[i] is a wave-broadcast L1 hit).
// Regular (cached) stores so L2 write-back coalesces the streams — nt stores
// caused 2.3x write amplification via HBM sector RMW (round-6 counters).

__global__ __launch_bounds__(256) void runend_kernel(
    const int* __restrict__ sub, int* __restrict__ re, int n) {
  int a = blockIdx.x * blockDim.x + threadIdx.x;
  if (a >= n) return;
  const int shift = (sub[n - 1] == 0) ? 1 : 0;  // int64 words vs int32
  int s = sub[a << shift];
  int lo = a + 1, hi = n;                        // first idx>a with sub>s
  while (lo < hi) {
    int mid = (lo + hi) >> 1;
    if (sub[mid << shift] > s) hi = mid; else lo = mid + 1;
  }
  re[a] = lo;
}

template <bool USE_RE>
__global__ __launch_bounds__(256) void pairlist_kernel(
    const float* __restrict__ pos, const int* __restrict__ sub,
    const int* __restrict__ runEnd, float* __restrict__ out,
    int n, long long P) {
  long long g  = (long long)blockIdx.x * blockDim.x + threadIdx.x;
  long long p0 = g * 4;
  if (p0 >= P) return;

  // Invert triangular linear index -> row i (double sqrt + exact fixup).
  double t = 2.0 * (double)n - 1.0;
  double disc = t * t - 8.0 * (double)p0;
  int i = (int)((t - sqrt(disc)) * 0.5);
  if (i < 0) i = 0;
  if (i > n - 2) i = n - 2;
  auto T = [n](long long ii) { return ii * (2LL * n - ii - 1) / 2; };
  while (T(i + 1) <= p0) ++i;
  while (i > 0 && T(i) > p0) --i;
  int j = (int)((long long)i + 1 + (p0 - T(i)));

  float* oi  = out;
  float* oj  = out + P;
  float* od  = out + 2 * P;
  float* orr = out + 3 * P;
  float* ov  = out + 6 * P;

  int shift = 0, re;
  if (USE_RE) {
    re = runEnd[i];
  } else {
    shift = (sub[n - 1] == 0) ? 1 : 0;
    re = (sub[j << shift] == sub[i << shift]) ? n : j;
  }

  // Fast path: all 4 pairs cross-subsystem, same row -> constants only.
  if (j >= re && p0 + 4 <= P && j + 4 <= n) {
    const float4 NEG = make_float4(-1.f, -1.f, -1.f, -1.f);
    const float4 ZER = make_float4(0.f, 0.f, 0.f, 0.f);
    *reinterpret_cast<float4*>(oi + p0) = NEG;
    *reinterpret_cast<float4*>(oj + p0) = NEG;
    *reinterpret_cast<float4*>(od + p0) = ZER;
    *reinterpret_cast<float4*>(ov + p0) = ZER;
    float4* rb = reinterpret_cast<float4*>(orr + 3 * p0);
    rb[0] = ZER; rb[1] = ZER; rb[2] = ZER;
    return;
  }

  int si = 0;
  if (!USE_RE) si = sub[i << shift];
  float pix = pos[3 * i], piy = pos[3 * i + 1], piz = pos[3 * i + 2];

  float fi[4], fj[4], fd[4], fv[4], fr[12];

#pragma unroll
  for (int k = 0; k < 4; ++k) {
    long long p = p0 + k;
    float vi = -1.0f, vj = -1.0f, vd = 0.0f, vv = 0.0f;
    float rx = 0.0f, ry = 0.0f, rz = 0.0f;
    if (p < P) {
      bool insys = USE_RE ? (j < re) : (sub[j << shift] == si);
      if (insys) {
        float dx = pos[3 * j]     - pix;
        float dy = pos[3 * j + 1] - piy;
        float dz = pos[3 * j + 2] - piz;
        float dd = sqrtf(dx * dx + dy * dy + dz * dz);
        if (dd < 5.0f) {
          vi = (float)i; vj = (float)j;
          vd = dd; vv = 1.0f;
          rx = dx; ry = dy; rz = dz;
        }
      }
      ++j;
      if (j >= n) {                       // row advance (rare)
        ++i;
        j = i + 1;
        if (i < n - 1) {
          if (USE_RE) re = runEnd[i];
          else        si = sub[i << shift];
          pix = pos[3 * i]; piy = pos[3 * i + 1]; piz = pos[3 * i + 2];
        }
      }
    }
    fi[k] = vi; fj[k] = vj; fd[k] = vd; fv[k] = vv;
    fr[3 * k] = rx; fr[3 * k + 1] = ry; fr[3 * k + 2] = rz;
  }

  if (p0 + 4 <= P) {
    *reinterpret_cast<float4*>(oi + p0) = make_float4(fi[0], fi[1], fi[2], fi[3]);
    *reinterpret_cast<float4*>(oj + p0) = make_float4(fj[0], fj[1], fj[2], fj[3]);
    *reinterpret_cast<float4*>(od + p0) = make_float4(fd[0], fd[1], fd[2], fd[3]);
    *reinterpret_cast<float4*>(ov + p0) = make_float4(fv[0], fv[1], fv[2], fv[3]);
    float4* rb = reinterpret_cast<float4*>(orr + 3 * p0);
    rb[0] = make_float4(fr[0], fr[1], fr[2],  fr[3]);
    rb[1] = make_float4(fr[4], fr[5], fr[6],  fr[7]);
    rb[2] = make_float4(fr[8], fr[9], fr[10], fr[11]);
  } else {
    for (int k = 0; k < 4 && p0 + k < P; ++k) {
      long long p = p0 + k;
      oi[p] = fi[k]; oj[p] = fj[k]; od[p] = fd[k]; ov[p] = fv[k];
      orr[3 * p] = fr[3 * k]; orr[3 * p + 1] = fr[3 * k + 1]; orr[3 * p + 2] = fr[3 * k + 2];
    }
  }
}

extern "C" void kernel_launch(void* const* d_in, const int* in_sizes, int n_in,
                              void* d_out, int out_size, void* d_ws, size_t ws_size,
                              hipStream_t stream) {
  const float* pos = (const float*)d_in[0];
  const int*   sub = (const int*)d_in[1];
  float* out = (float*)d_out;

  // Geometry from out_size: out_size = 7P, P = n(n-1)/2.
  long long P = (long long)out_size / 7;
  int n = (int)((1.0 + sqrt(1.0 + 8.0 * (double)P)) * 0.5 + 0.5);
  if ((long long)n * (n - 1) / 2 != P) {        // fallback
    n = in_sizes[0] / 3;
    P = (long long)n * (n - 1) / 2;
  }

  long long threads = (P + 3) / 4;
  int blocks = (int)((threads + 255) / 256);

  bool useRe = (ws_size >= (size_t)n * sizeof(int));
  if (useRe) {
    int* re = (int*)d_ws;
    hipLaunchKernelGGL(runend_kernel, dim3((n + 255) / 256), dim3(256), 0,
                       stream, sub, re, n);
    hipLaunchKernelGGL((pairlist_kernel<true>), dim3(blocks), dim3(256), 0,
                       stream, pos, sub, re, out, n, P);
  } else {
    hipLaunchKernelGGL((pairlist_kernel<false>), dim3(blocks), dim3(256), 0,
                       stream, pos, sub, (const int*)nullptr, out, n, P);
  }
}